// Round 5
// baseline (416.203 us; speedup 1.0000x reference)
//
#include <hip/hip_runtime.h>
#include <math.h>

typedef __attribute__((ext_vector_type(8))) short short8;
typedef __attribute__((ext_vector_type(4))) short short4e;
typedef __attribute__((ext_vector_type(4))) float floatx4;

__device__ __forceinline__ float sig(float z) { return 1.0f / (1.0f + __expf(-z)); }

__device__ __forceinline__ unsigned short f2bf(float f) {
    unsigned u = __float_as_uint(f);
    u = (u + 0x7FFFu + ((u >> 16) & 1u)) >> 16;   // RNE
    return (unsigned short)u;
}

// H x H fp32 (row-major [k][n]) -> bf16 pre-swizzled MFMA 16x16x32 B-frag order:
// blk = (n>>4)*(H/32) + (k>>5), lane = ((k>>3)&3)*16 + (n&15), j = k&7.
__global__ void convert_w1(const float* __restrict__ src, unsigned short* __restrict__ dst,
                           int H, int logH) {
    int idx = blockIdx.x * 256 + threadIdx.x;
    if (idx >= H * H) return;
    int n = idx & (H - 1), k = idx >> logH;
    int KT = H >> 5;
    int blk = (n >> 4) * KT + (k >> 5);
    int lane = ((k >> 3) & 3) * 16 + (n & 15);
    int j = k & 7;
    dst[(blk * 64 + lane) * 8 + j] = f2bf(src[idx]);
}

// ---------------- pos net: 7 -> 512 -> 512 -> 3 ----------------
// 32 samples/block (256 A-rows), 256 threads, 4 waves. Wave w owns rows [w*64,w*64+64).
// N chunks of 128 (np=0..3); K slices of 64 (kt=0..7) rebuilt on the fly.
// B slice staged to LDS once per (np,kt), shared by all waves.
__global__ __launch_bounds__(256, 2)
void pos_mfma(const float* __restrict__ x,
              const float* __restrict__ W0, const float* __restrict__ b0,
              const float* __restrict__ b1,
              const float* __restrict__ W2, const float* __restrict__ b2,
              const unsigned short* __restrict__ wsW1,
              float* __restrict__ out, int ns)
{
    extern __shared__ unsigned short sMem[];
    unsigned short* sA = sMem;              // 16 rtg x 2 ks x 64 x 8 = 16384 shorts (32 KB)
    unsigned short* sB = sMem + 16384;      // 8 ct x 2 ks x 64 x 8 = 8192 shorts (16 KB)
    __shared__ float sB0[512];
    __shared__ float sB1[512];
    __shared__ float sW2[1536];
    __shared__ float sQ[32][8];
    __shared__ float sQd[32][8];
    __shared__ float sSum[256][3];

    const int tid = threadIdx.x;
    const int m0  = blockIdx.x * 32;

    for (int i = tid; i < 512;  i += 256) { sB0[i] = b0[i]; sB1[i] = b1[i]; }
    for (int i = tid; i < 1536; i += 256) sW2[i] = W2[i];
    for (int idx = tid; idx < 448; idx += 256) {
        int m = idx / 14, c = idx % 14;
        float v = x[(m0 + m) * 14 + c];
        if (c < 7) sQ[m][c] = v; else sQd[m][c - 7] = v;
    }
    __syncthreads();

    const int w = tid >> 6, lane = tid & 63;
    const int quad = lane >> 4, col = lane & 15;
    const int srcl = lane & 47;
    const float4* W04 = (const float4*)W0;
    const floatx4 z4 = {0.f, 0.f, 0.f, 0.f};

    float ep[4][4][3];
    #pragma unroll
    for (int a = 0; a < 4; a++) for (int b = 0; b < 4; b++) for (int c = 0; c < 3; c++) ep[a][b][c] = 0.f;

    for (int np = 0; np < 4; ++np) {
        floatx4 acc[4][8];
        #pragma unroll
        for (int rt = 0; rt < 4; rt++)
            #pragma unroll
            for (int ct = 0; ct < 8; ct++) acc[rt][ct] = z4;

        for (int kt = 0; kt < 8; ++kt) {
            // ---- build A k-slice (k in [kt*64, kt*64+64)) ----
            #pragma unroll
            for (int it = 0; it < 2; ++it) {
                int idx = tid + it * 256;          // 512 items: (s, g)
                int s = idx >> 4, g = idx & 15;    // g: group of 4 k
                int kb = kt * 64 + g * 4;
                int ks = g >> 3, kq = (g >> 1) & 3, j0 = (g & 1) * 4;
                int f = kq | (ks << 2);
                float q[7]; float4 w0r[7];
                #pragma unroll
                for (int i = 0; i < 7; i++) { q[i] = sQ[s][i]; w0r[i] = W04[i * 128 + (kb >> 2)]; }
                float hv[4], dv[4];
                #pragma unroll
                for (int jj = 0; jj < 4; jj++) {
                    float z = sB0[kb + jj];
                    #pragma unroll
                    for (int i = 0; i < 7; i++) z = fmaf(q[i], ((const float*)&w0r[i])[jj], z);
                    float hh = sig(z);
                    hv[jj] = hh; dv[jj] = hh - hh * hh;
                }
                int r0 = s * 8;
                {
                    int rtg = r0 >> 4, r15 = r0 & 15;
                    int a16 = (rtg * 2 + ks) * 64 + kq * 16 + (r15 ^ f);
                    short4e v;
                    #pragma unroll
                    for (int jj = 0; jj < 4; jj++) v[jj] = (short)f2bf(hv[jj]);
                    *(short4e*)&sA[a16 * 8 + j0] = v;
                }
                #pragma unroll
                for (int i = 0; i < 7; i++) {
                    int rr = r0 + 1 + i;
                    int rtg = rr >> 4, r15 = rr & 15;
                    int a16 = (rtg * 2 + ks) * 64 + kq * 16 + (r15 ^ f);
                    short4e v;
                    #pragma unroll
                    for (int jj = 0; jj < 4; jj++) v[jj] = (short)f2bf(dv[jj] * ((const float*)&w0r[i])[jj]);
                    *(short4e*)&sA[a16 * 8 + j0] = v;
                }
            }
            // ---- stage B slice (np, kt): 16 KB ----
            #pragma unroll
            for (int p = 0; p < 4; ++p) {
                int idx = tid + p * 256;           // 1024 x 16B
                int ct = idx >> 7, ks = (idx >> 6) & 1, ll = idx & 63;
                size_t blk = (size_t)((np * 8 + ct) * 16 + kt * 2 + ks);
                short8 v = *(const short8*)(wsW1 + (blk * 64 + ll) * 8);
                *(short8*)&sB[((ct * 2 + ks) * 64 + ll) * 8] = v;
            }
            __syncthreads();
            // ---- MFMA ----
            short8 afr[4][2];
            #pragma unroll
            for (int rt = 0; rt < 4; ++rt) {
                int rtg = w * 4 + rt;
                #pragma unroll
                for (int ks = 0; ks < 2; ++ks) {
                    int a16 = (rtg * 2 + ks) * 64 + quad * 16 + (col ^ (quad | (ks << 2)));
                    afr[rt][ks] = *(const short8*)&sA[a16 * 8];
                }
            }
            #pragma unroll
            for (int ct = 0; ct < 8; ++ct) {
                short8 bf0 = *(const short8*)&sB[((ct * 2 + 0) * 64 + lane) * 8];
                short8 bf1 = *(const short8*)&sB[((ct * 2 + 1) * 64 + lane) * 8];
                #pragma unroll
                for (int rt = 0; rt < 4; ++rt) {
                    acc[rt][ct] = __builtin_amdgcn_mfma_f32_16x16x32_bf16(afr[rt][0], bf0, acc[rt][ct], 0, 0, 0);
                    acc[rt][ct] = __builtin_amdgcn_mfma_f32_16x16x32_bf16(afr[rt][1], bf1, acc[rt][ct], 0, 0, 0);
                }
            }
            __syncthreads();
        }
        // ---- epilogue for this N chunk: layer-2 partial contraction ----
        #pragma unroll
        for (int ct = 0; ct < 8; ++ct) {
            const int n = np * 128 + ct * 16 + col;
            const float b1n = sB1[n];
            const float w20 = sW2[n * 3], w21 = sW2[n * 3 + 1], w22 = sW2[n * 3 + 2];
            #pragma unroll
            for (int rt = 0; rt < 4; ++rt) {
                float z2c = __shfl(acc[rt][ct][0], srcl);
                float h2 = sig(z2c + b1n);
                float d2 = h2 - h2 * h2;
                #pragma unroll
                for (int r = 0; r < 4; ++r) {
                    float g2 = ((quad & 1) == 0 && r == 0) ? h2 : d2 * acc[rt][ct][r];
                    ep[rt][r][0] = fmaf(g2, w20, ep[rt][r][0]);
                    ep[rt][r][1] = fmaf(g2, w21, ep[rt][r][1]);
                    ep[rt][r][2] = fmaf(g2, w22, ep[rt][r][2]);
                }
            }
        }
    }

    #pragma unroll
    for (int mask = 1; mask <= 8; mask <<= 1)
        #pragma unroll
        for (int a = 0; a < 4; a++)
            #pragma unroll
            for (int b = 0; b < 4; b++)
                #pragma unroll
                for (int c = 0; c < 3; c++)
                    ep[a][b][c] += __shfl_xor(ep[a][b][c], mask);
    if (col == 0) {
        #pragma unroll
        for (int rt = 0; rt < 4; ++rt)
            #pragma unroll
            for (int r = 0; r < 4; ++r) {
                int row = w * 64 + rt * 16 + quad * 4 + r;
                sSum[row][0] = ep[rt][r][0];
                sSum[row][1] = ep[rt][r][1];
                sSum[row][2] = ep[rt][r][2];
            }
    }
    __syncthreads();

    const size_t JTOT = (size_t)ns * 18, OUTA = (size_t)ns * 81, JANG = (size_t)ns * 87;
    for (int e = tid; e < 768; e += 256) {
        int row = e / 3, j = e % 3;
        float v = sSum[row][j];
        int s = row >> 3, i = row & 7;
        size_t M = m0 + s;
        if (i == 0) { v += b2[j]; out[M * 18 + j] = v; out[OUTA + M * 6 + j] = v; }
        else        { out[JTOT + M * 63 + j * 7 + (i - 1)] = v;
                      out[JANG + M * 42 + j * 7 + (i - 1)] = v; }
    }
    if (tid < 96) {
        int s = tid / 3, j = tid % 3;
        float vel = 0.f;
        #pragma unroll
        for (int i = 0; i < 7; i++) vel = fmaf(sSum[s * 8 + 1 + i][j], sQd[s][i], vel);
        out[(size_t)(m0 + s) * 18 + 9 + j] = vel;
    }
}

// ---------------- rpy heads: 7 -> 256 -> 256 -> 2, blockIdx.y = head ----------------
// 32 samples/block (256 rows). N chunks of 128 (np=0..1), K slices of 64 (kt=0..3).
__global__ __launch_bounds__(256, 2)
void rpy_mfma(const float* __restrict__ x,
              const float* __restrict__ rW0, const float* __restrict__ rb0,
              const float* __restrict__ rb1,
              const float* __restrict__ rW2, const float* __restrict__ rb2,
              const float* __restrict__ pW0, const float* __restrict__ pb0,
              const float* __restrict__ pb1,
              const float* __restrict__ pW2, const float* __restrict__ pb2,
              const float* __restrict__ yW0, const float* __restrict__ yb0,
              const float* __restrict__ yb1,
              const float* __restrict__ yW2, const float* __restrict__ yb2,
              const unsigned short* __restrict__ wsBase,
              float* __restrict__ out, int ns)
{
    extern __shared__ unsigned short sMem[];
    unsigned short* sA = sMem;              // 32 KB
    unsigned short* sB = sMem + 16384;      // 16 KB
    __shared__ float sB0[256];
    __shared__ float sB1[256];
    __shared__ float sW2[512];
    __shared__ float sQ[32][8];
    __shared__ float sQd[32][8];
    __shared__ float sSum[256][2];

    const int tid = threadIdx.x;
    const int m0  = blockIdx.x * 32;
    const int h   = blockIdx.y;

    const float* W0 = (h == 0) ? rW0 : (h == 1) ? pW0 : yW0;
    const float* b0 = (h == 0) ? rb0 : (h == 1) ? pb0 : yb0;
    const float* b1 = (h == 0) ? rb1 : (h == 1) ? pb1 : yb1;
    const float* W2 = (h == 0) ? rW2 : (h == 1) ? pW2 : yW2;
    const float* b2 = (h == 0) ? rb2 : (h == 1) ? pb2 : yb2;
    const unsigned short* wsW1 = wsBase + 262144 + h * 65536;

    if (tid < 256) { sB0[tid] = b0[tid]; sB1[tid] = b1[tid]; }
    for (int i = tid; i < 512; i += 256) sW2[i] = W2[i];
    for (int idx = tid; idx < 448; idx += 256) {
        int m = idx / 14, c = idx % 14;
        float v = x[(m0 + m) * 14 + c];
        if (c < 7) sQ[m][c] = v; else sQd[m][c - 7] = v;
    }
    __syncthreads();

    const int w = tid >> 6, lane = tid & 63;
    const int quad = lane >> 4, col = lane & 15;
    const int srcl = lane & 47;
    const float4* W04 = (const float4*)W0;
    const floatx4 z4 = {0.f, 0.f, 0.f, 0.f};

    float ep[4][4][2];
    #pragma unroll
    for (int a = 0; a < 4; a++) for (int b = 0; b < 4; b++) for (int c = 0; c < 2; c++) ep[a][b][c] = 0.f;

    for (int np = 0; np < 2; ++np) {
        floatx4 acc[4][8];
        #pragma unroll
        for (int rt = 0; rt < 4; rt++)
            #pragma unroll
            for (int ct = 0; ct < 8; ct++) acc[rt][ct] = z4;

        for (int kt = 0; kt < 4; ++kt) {
            #pragma unroll
            for (int it = 0; it < 2; ++it) {
                int idx = tid + it * 256;
                int s = idx >> 4, g = idx & 15;
                int kb = kt * 64 + g * 4;
                int ks = g >> 3, kq = (g >> 1) & 3, j0 = (g & 1) * 4;
                int f = kq | (ks << 2);
                float q[7]; float4 w0r[7];
                #pragma unroll
                for (int i = 0; i < 7; i++) { q[i] = sQ[s][i]; w0r[i] = W04[i * 64 + (kb >> 2)]; }
                float hv[4], dv[4];
                #pragma unroll
                for (int jj = 0; jj < 4; jj++) {
                    float z = sB0[kb + jj];
                    #pragma unroll
                    for (int i = 0; i < 7; i++) z = fmaf(q[i], ((const float*)&w0r[i])[jj], z);
                    float hh = sig(z);
                    hv[jj] = hh; dv[jj] = hh - hh * hh;
                }
                int r0 = s * 8;
                {
                    int rtg = r0 >> 4, r15 = r0 & 15;
                    int a16 = (rtg * 2 + ks) * 64 + kq * 16 + (r15 ^ f);
                    short4e v;
                    #pragma unroll
                    for (int jj = 0; jj < 4; jj++) v[jj] = (short)f2bf(hv[jj]);
                    *(short4e*)&sA[a16 * 8 + j0] = v;
                }
                #pragma unroll
                for (int i = 0; i < 7; i++) {
                    int rr = r0 + 1 + i;
                    int rtg = rr >> 4, r15 = rr & 15;
                    int a16 = (rtg * 2 + ks) * 64 + kq * 16 + (r15 ^ f);
                    short4e v;
                    #pragma unroll
                    for (int jj = 0; jj < 4; jj++) v[jj] = (short)f2bf(dv[jj] * ((const float*)&w0r[i])[jj]);
                    *(short4e*)&sA[a16 * 8 + j0] = v;
                }
            }
            #pragma unroll
            for (int p = 0; p < 4; ++p) {
                int idx = tid + p * 256;
                int ct = idx >> 7, ks = (idx >> 6) & 1, ll = idx & 63;
                size_t blk = (size_t)((np * 8 + ct) * 8 + kt * 2 + ks);
                short8 v = *(const short8*)(wsW1 + (blk * 64 + ll) * 8);
                *(short8*)&sB[((ct * 2 + ks) * 64 + ll) * 8] = v;
            }
            __syncthreads();
            short8 afr[4][2];
            #pragma unroll
            for (int rt = 0; rt < 4; ++rt) {
                int rtg = w * 4 + rt;
                #pragma unroll
                for (int ks = 0; ks < 2; ++ks) {
                    int a16 = (rtg * 2 + ks) * 64 + quad * 16 + (col ^ (quad | (ks << 2)));
                    afr[rt][ks] = *(const short8*)&sA[a16 * 8];
                }
            }
            #pragma unroll
            for (int ct = 0; ct < 8; ++ct) {
                short8 bf0 = *(const short8*)&sB[((ct * 2 + 0) * 64 + lane) * 8];
                short8 bf1 = *(const short8*)&sB[((ct * 2 + 1) * 64 + lane) * 8];
                #pragma unroll
                for (int rt = 0; rt < 4; ++rt) {
                    acc[rt][ct] = __builtin_amdgcn_mfma_f32_16x16x32_bf16(afr[rt][0], bf0, acc[rt][ct], 0, 0, 0);
                    acc[rt][ct] = __builtin_amdgcn_mfma_f32_16x16x32_bf16(afr[rt][1], bf1, acc[rt][ct], 0, 0, 0);
                }
            }
            __syncthreads();
        }
        #pragma unroll
        for (int ct = 0; ct < 8; ++ct) {
            const int n = np * 128 + ct * 16 + col;
            const float b1n = sB1[n];
            const float w20 = sW2[n * 2], w21 = sW2[n * 2 + 1];
            #pragma unroll
            for (int rt = 0; rt < 4; ++rt) {
                float z2c = __shfl(acc[rt][ct][0], srcl);
                float h2 = sig(z2c + b1n);
                float d2 = h2 - h2 * h2;
                #pragma unroll
                for (int r = 0; r < 4; ++r) {
                    float g2 = ((quad & 1) == 0 && r == 0) ? h2 : d2 * acc[rt][ct][r];
                    ep[rt][r][0] = fmaf(g2, w20, ep[rt][r][0]);
                    ep[rt][r][1] = fmaf(g2, w21, ep[rt][r][1]);
                }
            }
        }
    }

    #pragma unroll
    for (int mask = 1; mask <= 8; mask <<= 1)
        #pragma unroll
        for (int a = 0; a < 4; a++)
            #pragma unroll
            for (int b = 0; b < 4; b++)
                #pragma unroll
                for (int c = 0; c < 2; c++)
                    ep[a][b][c] += __shfl_xor(ep[a][b][c], mask);
    if (col == 0) {
        #pragma unroll
        for (int rt = 0; rt < 4; ++rt)
            #pragma unroll
            for (int r = 0; r < 4; ++r) {
                int row = w * 64 + rt * 16 + quad * 4 + r;
                sSum[row][0] = ep[rt][r][0];
                sSum[row][1] = ep[rt][r][1];
            }
    }
    __syncthreads();

    const size_t JTOT = (size_t)ns * 18, OUTA = (size_t)ns * 81, JANG = (size_t)ns * 87;
    if (tid < 32) {
        int s = tid;
        size_t M = m0 + s;
        float y0 = sSum[s * 8][0] + b2[0], y1 = sSum[s * 8][1] + b2[1];
        float sv = sinf(y0), cv = cosf(y1);
        out[M * 18 + 3 + h] = sv;
        out[M * 18 + 6 + h] = cv;
        out[OUTA + M * 6 + 3 + h] = atan2f(sv, cv);
        float f0 = cosf(y0), f1 = -sinf(y1);
        float inv = 1.0f / fmaf(sv, sv, cv * cv);
        float v0 = 0.f, v1 = 0.f;
        #pragma unroll
        for (int i = 0; i < 7; i++) {
            float r0 = f0 * sSum[s * 8 + 1 + i][0];
            float r1 = f1 * sSum[s * 8 + 1 + i][1];
            out[JTOT + M * 63 + (3 + h) * 7 + i] = r0;
            out[JTOT + M * 63 + (6 + h) * 7 + i] = r1;
            out[JANG + M * 42 + (3 + h) * 7 + i] = (cv * r0 - sv * r1) * inv;
            v0 = fmaf(r0, sQd[s][i], v0);
            v1 = fmaf(r1, sQd[s][i], v1);
        }
        out[M * 18 + 12 + h] = v0;
        out[M * 18 + 15 + h] = v1;
    }
}

extern "C" void kernel_launch(void* const* d_in, const int* in_sizes, int n_in,
                              void* d_out, int out_size, void* d_ws, size_t ws_size,
                              hipStream_t stream) {
    (void)n_in; (void)out_size; (void)ws_size;
    const float* x = (const float*)d_in[0];
    float* out = (float*)d_out;
    unsigned short* ws = (unsigned short*)d_ws;
    const int ns = in_sizes[0] / 14;

    convert_w1<<<dim3((512 * 512) / 256), 256, 0, stream>>>((const float*)d_in[3],  ws,          512, 9);
    convert_w1<<<dim3((256 * 256) / 256), 256, 0, stream>>>((const float*)d_in[9],  ws + 262144, 256, 8);
    convert_w1<<<dim3((256 * 256) / 256), 256, 0, stream>>>((const float*)d_in[15], ws + 327680, 256, 8);
    convert_w1<<<dim3((256 * 256) / 256), 256, 0, stream>>>((const float*)d_in[21], ws + 393216, 256, 8);

    pos_mfma<<<dim3(ns / 32), 256, 49152, stream>>>(
        x,
        (const float*)d_in[1], (const float*)d_in[2],
        (const float*)d_in[4],
        (const float*)d_in[5], (const float*)d_in[6],
        ws, out, ns);

    rpy_mfma<<<dim3(ns / 32, 3), 256, 49152, stream>>>(
        x,
        (const float*)d_in[7],  (const float*)d_in[8],  (const float*)d_in[10],
        (const float*)d_in[11], (const float*)d_in[12],
        (const float*)d_in[13], (const float*)d_in[14], (const float*)d_in[16],
        (const float*)d_in[17], (const float*)d_in[18],
        (const float*)d_in[19], (const float*)d_in[20], (const float*)d_in[22],
        (const float*)d_in[23], (const float*)d_in[24],
        ws, out, ns);
}

// Round 6
// 338.387 us; speedup vs baseline: 1.2300x; 1.2300x over previous
//
#include <hip/hip_runtime.h>
#include <math.h>

typedef __attribute__((ext_vector_type(8))) short short8;
typedef __attribute__((ext_vector_type(4))) float floatx4;

__device__ __forceinline__ float sig(float z) { return 1.0f / (1.0f + __expf(-z)); }

__device__ __forceinline__ unsigned short f2bf(float f) {
    unsigned u = __float_as_uint(f);
    u = (u + 0x7FFFu + ((u >> 16) & 1u)) >> 16;   // RNE
    return (unsigned short)u;
}

// H x H fp32 (row-major [k][n]) -> bf16 pre-swizzled MFMA 16x16x32 B-frag order:
// blk = (n>>4)*(H/32) + (k>>5), lane = ((k>>3)&3)*16 + (n&15), j = k&7.
__global__ void convert_w1(const float* __restrict__ src, unsigned short* __restrict__ dst,
                           int H, int logH) {
    int idx = blockIdx.x * 256 + threadIdx.x;
    if (idx >= H * H) return;
    int n = idx & (H - 1), k = idx >> logH;
    int KT = H >> 5;
    int blk = (n >> 4) * KT + (k >> 5);
    int lane = ((k >> 3) & 3) * 16 + (n & 15);
    int j = k & 7;
    dst[(blk * 64 + lane) * 8 + j] = f2bf(src[idx]);
}

// ---------------- pos net: 7 -> 512 -> 512 -> 3 ----------------
// 8 samples/block (M=64 rows), 256 threads. Wave w owns ALL 4 row-tiles and
// the N-quarter [w*128, w*128+128) -> B read exactly once per block.
// kt outer, B register ping-pong prefetch; A built once in LDS (XOR-swizzled).
__global__ __launch_bounds__(256, 2)
void pos_mfma(const float* __restrict__ x,
              const float* __restrict__ W0, const float* __restrict__ b0,
              const float* __restrict__ b1,
              const float* __restrict__ W2, const float* __restrict__ b2,
              const unsigned short* __restrict__ wsW1,
              float* __restrict__ out, int ns)
{
    extern __shared__ unsigned short sA[];      // 32768 shorts = 64 KB
    __shared__ float sB0[512];
    __shared__ float sB1[512];
    __shared__ float sW2[1536];
    __shared__ float sQ[8][8];
    __shared__ float sQd[8][8];
    __shared__ float sAcc[4][64][3];
    __shared__ float sSum[64][3];

    const int tid = threadIdx.x;
    const int m0  = blockIdx.x * 8;

    for (int i = tid; i < 512;  i += 256) { sB0[i] = b0[i]; sB1[i] = b1[i]; }
    for (int i = tid; i < 1536; i += 256) sW2[i] = W2[i];
    if (tid < 112) {
        int m = tid / 14, c = tid % 14;
        float v = x[(m0 + m) * 14 + c];
        if (c < 7) sQ[m][c] = v; else sQd[m][c - 7] = v;
    }
    __syncthreads();

    // Build A (h1 row + 7 tangent rows per sample) in kt-XOR-swizzled fragment order.
    const float4* W04 = (const float4*)W0;
    #pragma unroll
    for (int t = 0; t < 2; ++t) {
        int item = tid + t * 256;            // 512 items: (s, k8)
        int s = item >> 6, k8 = item & 63;
        float q[7], w0v[7][8];
        #pragma unroll
        for (int i = 0; i < 7; i++) {
            q[i] = sQ[s][i];
            float4 a = W04[i * 128 + k8 * 2], b4 = W04[i * 128 + k8 * 2 + 1];
            w0v[i][0]=a.x; w0v[i][1]=a.y; w0v[i][2]=a.z; w0v[i][3]=a.w;
            w0v[i][4]=b4.x; w0v[i][5]=b4.y; w0v[i][6]=b4.z; w0v[i][7]=b4.w;
        }
        float hv[8], dv[8];
        #pragma unroll
        for (int jj = 0; jj < 8; jj++) {
            float z = sB0[k8 * 8 + jj];
            #pragma unroll
            for (int i = 0; i < 7; i++) z = fmaf(q[i], w0v[i][jj], z);
            float h = sig(z);
            hv[jj] = h; dv[jj] = h - h * h;
        }
        int kt = k8 >> 2, kq = k8 & 3, sw = kt & 7;
        int rr0 = s * 8;
        {
            short8 v;
            #pragma unroll
            for (int jj = 0; jj < 8; jj++) v[jj] = (short)f2bf(hv[jj]);
            *(short8*)&sA[((rr0 >> 4) * 16 + kt) * 512 + ((kq * 16 + (rr0 & 15)) ^ sw) * 8] = v;
        }
        #pragma unroll
        for (int i = 0; i < 7; i++) {
            int rr = rr0 + 1 + i;
            short8 v;
            #pragma unroll
            for (int jj = 0; jj < 8; jj++) v[jj] = (short)f2bf(dv[jj] * w0v[i][jj]);
            *(short8*)&sA[((rr >> 4) * 16 + kt) * 512 + ((kq * 16 + (rr & 15)) ^ sw) * 8] = v;
        }
    }
    __syncthreads();

    const int w = tid >> 6, lane = tid & 63;
    const int quad = lane >> 4, col = lane & 15;
    const int srcl = lane & 47;
    const floatx4 z4 = {0.f, 0.f, 0.f, 0.f};

    floatx4 acc[4][8];
    #pragma unroll
    for (int rt = 0; rt < 4; rt++)
        #pragma unroll
        for (int ct = 0; ct < 8; ct++) acc[rt][ct] = z4;

    // B frag (ct,kt) at bbase + (ct*16 + kt)*64
    const short8* bbase = (const short8*)wsW1 + (size_t)(w * 8 * 16) * 64 + lane;

    short8 bufA[8], bufB[8];
    #pragma unroll
    for (int ct = 0; ct < 8; ++ct) bufA[ct] = bbase[(ct * 16) * 64];

    for (int kt2 = 0; kt2 < 16; kt2 += 2) {
        #pragma unroll
        for (int ct = 0; ct < 8; ++ct) bufB[ct] = bbase[(ct * 16 + kt2 + 1) * 64];
        {
            const int kt = kt2, sw = kt & 7;
            short8 afr[4];
            #pragma unroll
            for (int rt = 0; rt < 4; ++rt)
                afr[rt] = *(const short8*)&sA[(rt * 16 + kt) * 512 + (lane ^ sw) * 8];
            #pragma unroll
            for (int ct = 0; ct < 8; ++ct)
                #pragma unroll
                for (int rt = 0; rt < 4; ++rt)
                    acc[rt][ct] = __builtin_amdgcn_mfma_f32_16x16x32_bf16(afr[rt], bufA[ct], acc[rt][ct], 0, 0, 0);
        }
        if (kt2 + 2 < 16) {
            #pragma unroll
            for (int ct = 0; ct < 8; ++ct) bufA[ct] = bbase[(ct * 16 + kt2 + 2) * 64];
        }
        {
            const int kt = kt2 + 1, sw = kt & 7;
            short8 afr[4];
            #pragma unroll
            for (int rt = 0; rt < 4; ++rt)
                afr[rt] = *(const short8*)&sA[(rt * 16 + kt) * 512 + (lane ^ sw) * 8];
            #pragma unroll
            for (int ct = 0; ct < 8; ++ct)
                #pragma unroll
                for (int rt = 0; rt < 4; ++rt)
                    acc[rt][ct] = __builtin_amdgcn_mfma_f32_16x16x32_bf16(afr[rt], bufB[ct], acc[rt][ct], 0, 0, 0);
        }
    }

    // epilogue: layer-2 contraction (wave covers cols [w*128, w*128+128))
    float ep[4][4][3];
    #pragma unroll
    for (int a = 0; a < 4; a++) for (int b = 0; b < 4; b++) for (int c = 0; c < 3; c++) ep[a][b][c] = 0.f;

    #pragma unroll
    for (int ct = 0; ct < 8; ++ct) {
        const int n = w * 128 + ct * 16 + col;
        const float b1n = sB1[n];
        const float w20 = sW2[n * 3], w21 = sW2[n * 3 + 1], w22 = sW2[n * 3 + 2];
        #pragma unroll
        for (int rt = 0; rt < 4; ++rt) {
            float z2c = __shfl(acc[rt][ct][0], srcl);
            float h2 = sig(z2c + b1n);
            float d2 = h2 - h2 * h2;
            #pragma unroll
            for (int r = 0; r < 4; ++r) {
                float g = ((quad & 1) == 0 && r == 0) ? h2 : d2 * acc[rt][ct][r];
                ep[rt][r][0] = fmaf(g, w20, ep[rt][r][0]);
                ep[rt][r][1] = fmaf(g, w21, ep[rt][r][1]);
                ep[rt][r][2] = fmaf(g, w22, ep[rt][r][2]);
            }
        }
    }

    #pragma unroll
    for (int mask = 1; mask <= 8; mask <<= 1)
        #pragma unroll
        for (int a = 0; a < 4; a++)
            #pragma unroll
            for (int b = 0; b < 4; b++)
                #pragma unroll
                for (int c = 0; c < 3; c++)
                    ep[a][b][c] += __shfl_xor(ep[a][b][c], mask);
    if (col == 0) {
        #pragma unroll
        for (int rt = 0; rt < 4; ++rt)
            #pragma unroll
            for (int r = 0; r < 4; ++r) {
                int row = rt * 16 + quad * 4 + r;
                sAcc[w][row][0] = ep[rt][r][0];
                sAcc[w][row][1] = ep[rt][r][1];
                sAcc[w][row][2] = ep[rt][r][2];
            }
    }
    __syncthreads();

    const size_t JTOT = (size_t)ns * 18, OUTA = (size_t)ns * 81, JANG = (size_t)ns * 87;
    if (tid < 192) {
        int row = tid / 3, j = tid % 3;
        float v = sAcc[0][row][j] + sAcc[1][row][j] + sAcc[2][row][j] + sAcc[3][row][j];
        int s = row >> 3, i = row & 7;
        size_t M = m0 + s;
        if (i == 0) { v += b2[j]; out[M * 18 + j] = v; out[OUTA + M * 6 + j] = v; }
        else        { out[JTOT + M * 63 + j * 7 + (i - 1)] = v;
                      out[JANG + M * 42 + j * 7 + (i - 1)] = v; }
        sSum[row][j] = v;
    }
    __syncthreads();
    if (tid < 24) {
        int s = tid / 3, j = tid % 3;
        float vel = 0.f;
        #pragma unroll
        for (int i = 0; i < 7; i++) vel = fmaf(sSum[s * 8 + 1 + i][j], sQd[s][i], vel);
        out[(size_t)(m0 + s) * 18 + 9 + j] = vel;
    }
}

// ---------------- rpy heads: 7 -> 256 -> 256 -> 2, blockIdx.y = head ----------------
// 16 samples/block (M=128 rows), 256 threads. Wave w owns ALL 8 row-tiles and
// the N-quarter [w*64, w*64+64) -> B read once per block. acc[8][4] = 128 AGPRs.
__global__ __launch_bounds__(256, 2)
void rpy_mfma(const float* __restrict__ x,
              const float* __restrict__ rW0, const float* __restrict__ rb0,
              const float* __restrict__ rb1,
              const float* __restrict__ rW2, const float* __restrict__ rb2,
              const float* __restrict__ pW0, const float* __restrict__ pb0,
              const float* __restrict__ pb1,
              const float* __restrict__ pW2, const float* __restrict__ pb2,
              const float* __restrict__ yW0, const float* __restrict__ yb0,
              const float* __restrict__ yb1,
              const float* __restrict__ yW2, const float* __restrict__ yb2,
              const unsigned short* __restrict__ wsBase,
              float* __restrict__ out, int ns)
{
    extern __shared__ unsigned short sA[];      // 64 KB (128 rows x 256 k)
    __shared__ float sB0[256];
    __shared__ float sB1[256];
    __shared__ float sW2[512];
    __shared__ float sQ[16][8];
    __shared__ float sQd[16][8];
    __shared__ float sAcc[4][128][2];
    __shared__ float sSum[128][2];

    const int tid = threadIdx.x;
    const int m0  = blockIdx.x * 16;
    const int h   = blockIdx.y;

    const float* W0 = (h == 0) ? rW0 : (h == 1) ? pW0 : yW0;
    const float* b0 = (h == 0) ? rb0 : (h == 1) ? pb0 : yb0;
    const float* b1 = (h == 0) ? rb1 : (h == 1) ? pb1 : yb1;
    const float* W2 = (h == 0) ? rW2 : (h == 1) ? pW2 : yW2;
    const float* b2 = (h == 0) ? rb2 : (h == 1) ? pb2 : yb2;
    const unsigned short* wsW1 = wsBase + 262144 + h * 65536;

    if (tid < 256) { sB0[tid] = b0[tid]; sB1[tid] = b1[tid]; }
    for (int i = tid; i < 512; i += 256) sW2[i] = W2[i];
    if (tid < 224) {
        int m = tid / 14, c = tid % 14;
        float v = x[(m0 + m) * 14 + c];
        if (c < 7) sQ[m][c] = v; else sQd[m][c - 7] = v;
    }
    __syncthreads();

    const float4* W04 = (const float4*)W0;
    #pragma unroll
    for (int t = 0; t < 2; ++t) {
        int item = tid + t * 256;            // 512 items: (s in 0..15, k8 in 0..31)
        int s = item >> 5, k8 = item & 31;
        float q[7], w0v[7][8];
        #pragma unroll
        for (int i = 0; i < 7; i++) {
            q[i] = sQ[s][i];
            float4 a = W04[i * 64 + k8 * 2], b4 = W04[i * 64 + k8 * 2 + 1];
            w0v[i][0]=a.x; w0v[i][1]=a.y; w0v[i][2]=a.z; w0v[i][3]=a.w;
            w0v[i][4]=b4.x; w0v[i][5]=b4.y; w0v[i][6]=b4.z; w0v[i][7]=b4.w;
        }
        float hv[8], dv[8];
        #pragma unroll
        for (int jj = 0; jj < 8; jj++) {
            float z = sB0[k8 * 8 + jj];
            #pragma unroll
            for (int i = 0; i < 7; i++) z = fmaf(q[i], w0v[i][jj], z);
            float hh = sig(z);
            hv[jj] = hh; dv[jj] = hh - hh * hh;
        }
        int kt = k8 >> 2, kq = k8 & 3, sw = kt & 7;
        int rr0 = s * 8;
        {
            short8 v;
            #pragma unroll
            for (int jj = 0; jj < 8; jj++) v[jj] = (short)f2bf(hv[jj]);
            *(short8*)&sA[((rr0 >> 4) * 8 + kt) * 512 + ((kq * 16 + (rr0 & 15)) ^ sw) * 8] = v;
        }
        #pragma unroll
        for (int i = 0; i < 7; i++) {
            int rr = rr0 + 1 + i;
            short8 v;
            #pragma unroll
            for (int jj = 0; jj < 8; jj++) v[jj] = (short)f2bf(dv[jj] * w0v[i][jj]);
            *(short8*)&sA[((rr >> 4) * 8 + kt) * 512 + ((kq * 16 + (rr & 15)) ^ sw) * 8] = v;
        }
    }
    __syncthreads();

    const int w = tid >> 6, lane = tid & 63;
    const int quad = lane >> 4, col = lane & 15;
    const int srcl = lane & 47;
    const floatx4 z4 = {0.f, 0.f, 0.f, 0.f};

    floatx4 acc[8][4];
    #pragma unroll
    for (int rt = 0; rt < 8; rt++)
        #pragma unroll
        for (int ct = 0; ct < 4; ct++) acc[rt][ct] = z4;

    // B frag (ct,kt) at bbase + (ct*8 + kt)*64
    const short8* bbase = (const short8*)wsW1 + (size_t)(w * 4 * 8) * 64 + lane;

    short8 bufA[4], bufB[4];
    #pragma unroll
    for (int ct = 0; ct < 4; ++ct) bufA[ct] = bbase[(ct * 8) * 64];

    for (int kt2 = 0; kt2 < 8; kt2 += 2) {
        #pragma unroll
        for (int ct = 0; ct < 4; ++ct) bufB[ct] = bbase[(ct * 8 + kt2 + 1) * 64];
        {
            const int kt = kt2, sw = kt & 7;
            short8 afr[8];
            #pragma unroll
            for (int rt = 0; rt < 8; ++rt)
                afr[rt] = *(const short8*)&sA[(rt * 8 + kt) * 512 + (lane ^ sw) * 8];
            #pragma unroll
            for (int ct = 0; ct < 4; ++ct)
                #pragma unroll
                for (int rt = 0; rt < 8; ++rt)
                    acc[rt][ct] = __builtin_amdgcn_mfma_f32_16x16x32_bf16(afr[rt], bufA[ct], acc[rt][ct], 0, 0, 0);
        }
        if (kt2 + 2 < 8) {
            #pragma unroll
            for (int ct = 0; ct < 4; ++ct) bufA[ct] = bbase[(ct * 8 + kt2 + 2) * 64];
        }
        {
            const int kt = kt2 + 1, sw = kt & 7;
            short8 afr[8];
            #pragma unroll
            for (int rt = 0; rt < 8; ++rt)
                afr[rt] = *(const short8*)&sA[(rt * 8 + kt) * 512 + (lane ^ sw) * 8];
            #pragma unroll
            for (int ct = 0; ct < 4; ++ct)
                #pragma unroll
                for (int rt = 0; rt < 8; ++rt)
                    acc[rt][ct] = __builtin_amdgcn_mfma_f32_16x16x32_bf16(afr[rt], bufB[ct], acc[rt][ct], 0, 0, 0);
        }
    }

    float ep[8][4][2];
    #pragma unroll
    for (int a = 0; a < 8; a++) for (int b = 0; b < 4; b++) for (int c = 0; c < 2; c++) ep[a][b][c] = 0.f;

    #pragma unroll
    for (int ct = 0; ct < 4; ++ct) {
        const int n = w * 64 + ct * 16 + col;
        const float b1n = sB1[n];
        const float w20 = sW2[n * 2], w21 = sW2[n * 2 + 1];
        #pragma unroll
        for (int rt = 0; rt < 8; ++rt) {
            float z2c = __shfl(acc[rt][ct][0], srcl);
            float h2 = sig(z2c + b1n);
            float d2 = h2 - h2 * h2;
            #pragma unroll
            for (int r = 0; r < 4; ++r) {
                float g = ((quad & 1) == 0 && r == 0) ? h2 : d2 * acc[rt][ct][r];
                ep[rt][r][0] = fmaf(g, w20, ep[rt][r][0]);
                ep[rt][r][1] = fmaf(g, w21, ep[rt][r][1]);
            }
        }
    }

    #pragma unroll
    for (int mask = 1; mask <= 8; mask <<= 1)
        #pragma unroll
        for (int a = 0; a < 8; a++)
            #pragma unroll
            for (int b = 0; b < 4; b++)
                #pragma unroll
                for (int c = 0; c < 2; c++)
                    ep[a][b][c] += __shfl_xor(ep[a][b][c], mask);
    if (col == 0) {
        #pragma unroll
        for (int rt = 0; rt < 8; ++rt)
            #pragma unroll
            for (int r = 0; r < 4; ++r) {
                int row = rt * 16 + quad * 4 + r;
                sAcc[w][row][0] = ep[rt][r][0];
                sAcc[w][row][1] = ep[rt][r][1];
            }
    }
    __syncthreads();

    if (tid < 256) {
        int row = tid >> 1, j = tid & 1;
        float v = sAcc[0][row][j] + sAcc[1][row][j] + sAcc[2][row][j] + sAcc[3][row][j];
        if ((row & 7) == 0) v += b2[j];
        sSum[row][j] = v;
    }
    __syncthreads();

    const size_t JTOT = (size_t)ns * 18, OUTA = (size_t)ns * 81, JANG = (size_t)ns * 87;
    if (tid < 16) {
        int s = tid;
        size_t M = m0 + s;
        float y0 = sSum[s * 8][0], y1 = sSum[s * 8][1];
        float sv = sinf(y0), cv = cosf(y1);
        out[M * 18 + 3 + h] = sv;
        out[M * 18 + 6 + h] = cv;
        out[OUTA + M * 6 + 3 + h] = atan2f(sv, cv);
        float f0 = cosf(y0), f1 = -sinf(y1);
        float inv = 1.0f / fmaf(sv, sv, cv * cv);
        float v0 = 0.f, v1 = 0.f;
        #pragma unroll
        for (int i = 0; i < 7; i++) {
            float r0 = f0 * sSum[s * 8 + 1 + i][0];
            float r1 = f1 * sSum[s * 8 + 1 + i][1];
            out[JTOT + M * 63 + (3 + h) * 7 + i] = r0;
            out[JTOT + M * 63 + (6 + h) * 7 + i] = r1;
            out[JANG + M * 42 + (3 + h) * 7 + i] = (cv * r0 - sv * r1) * inv;
            v0 = fmaf(r0, sQd[s][i], v0);
            v1 = fmaf(r1, sQd[s][i], v1);
        }
        out[M * 18 + 12 + h] = v0;
        out[M * 18 + 15 + h] = v1;
    }
}

extern "C" void kernel_launch(void* const* d_in, const int* in_sizes, int n_in,
                              void* d_out, int out_size, void* d_ws, size_t ws_size,
                              hipStream_t stream) {
    (void)n_in; (void)out_size; (void)ws_size;
    const float* x = (const float*)d_in[0];
    float* out = (float*)d_out;
    unsigned short* ws = (unsigned short*)d_ws;
    const int ns = in_sizes[0] / 14;

    convert_w1<<<dim3((512 * 512) / 256), 256, 0, stream>>>((const float*)d_in[3],  ws,          512, 9);
    convert_w1<<<dim3((256 * 256) / 256), 256, 0, stream>>>((const float*)d_in[9],  ws + 262144, 256, 8);
    convert_w1<<<dim3((256 * 256) / 256), 256, 0, stream>>>((const float*)d_in[15], ws + 327680, 256, 8);
    convert_w1<<<dim3((256 * 256) / 256), 256, 0, stream>>>((const float*)d_in[21], ws + 393216, 256, 8);

    pos_mfma<<<dim3(ns / 8), 256, 65536, stream>>>(
        x,
        (const float*)d_in[1], (const float*)d_in[2],
        (const float*)d_in[4],
        (const float*)d_in[5], (const float*)d_in[6],
        ws, out, ns);

    rpy_mfma<<<dim3(ns / 16, 3), 256, 65536, stream>>>(
        x,
        (const float*)d_in[7],  (const float*)d_in[8],  (const float*)d_in[10],
        (const float*)d_in[11], (const float*)d_in[12],
        (const float*)d_in[13], (const float*)d_in[14], (const float*)d_in[16],
        (const float*)d_in[17], (const float*)d_in[18],
        (const float*)d_in[19], (const float*)d_in[20], (const float*)d_in[22],
        (const float*)d_in[23], (const float*)d_in[24],
        ws, out, ns);
}

// Round 7
// 335.940 us; speedup vs baseline: 1.2389x; 1.0073x over previous
//
#include <hip/hip_runtime.h>
#include <math.h>

typedef __attribute__((ext_vector_type(8))) short short8;
typedef __attribute__((ext_vector_type(4))) float floatx4;

__device__ __forceinline__ float sig(float z) { return 1.0f / (1.0f + __expf(-z)); }

__device__ __forceinline__ unsigned short f2bf(float f) {
    unsigned u = __float_as_uint(f);
    u = (u + 0x7FFFu + ((u >> 16) & 1u)) >> 16;   // RNE
    return (unsigned short)u;
}

// H x H fp32 (row-major [k][n]) -> bf16 pre-swizzled MFMA 16x16x32 B-frag order:
// blk = (n>>4)*(H/32) + (k>>5), lane = ((k>>3)&3)*16 + (n&15), j = k&7.
__global__ void convert_w1(const float* __restrict__ src, unsigned short* __restrict__ dst,
                           int H, int logH) {
    int idx = blockIdx.x * 256 + threadIdx.x;
    if (idx >= H * H) return;
    int n = idx & (H - 1), k = idx >> logH;
    int KT = H >> 5;
    int blk = (n >> 4) * KT + (k >> 5);
    int lane = ((k >> 3) & 3) * 16 + (n & 15);
    int j = k & 7;
    dst[(blk * 64 + lane) * 8 + j] = f2bf(src[idx]);
}

struct PosS {
    float B0[512], B1[512], W2[1536];
    float Q[8][8], Qd[8][8];
    float Acc[4][64][3], Sum[64][3];
};
struct RpyS {
    float B0[256], B1[256], W2[512];
    float Q[16][8], Qd[16][8];
    float Acc[4][128][2], Sum[128][2];
};

// Fused kernel: 5120 blocks. f%5<2 -> pos sample-tile (2048 of them, 8 samples each);
// f%5>=2 -> rpy (head = f%5-2, 1024 sample-tiles of 16 samples). Interleaving keeps
// pos and rpy blocks co-resident on every CU so their stall phases overlap.
__global__ __launch_bounds__(256, 2)
void fused_mfma(const float* __restrict__ x,
                const float* __restrict__ pW0, const float* __restrict__ pb0,
                const float* __restrict__ pb1,
                const float* __restrict__ pW2, const float* __restrict__ pb2,
                const float* __restrict__ rW0_, const float* __restrict__ rb0_,
                const float* __restrict__ rb1_,
                const float* __restrict__ rW2_, const float* __restrict__ rb2_,
                const float* __restrict__ piW0, const float* __restrict__ pib0,
                const float* __restrict__ pib1,
                const float* __restrict__ piW2, const float* __restrict__ pib2,
                const float* __restrict__ yW0, const float* __restrict__ yb0,
                const float* __restrict__ yb1,
                const float* __restrict__ yW2, const float* __restrict__ yb2,
                const unsigned short* __restrict__ wsBase,
                float* __restrict__ out, int ns)
{
    extern __shared__ unsigned short sA[];      // 64 KB dynamic
    __shared__ union { PosS p; RpyS r; } sU;

    const int tid = threadIdx.x;
    const int f = blockIdx.x;
    const int g = f / 5, r5 = f % 5;
    const size_t JTOT = (size_t)ns * 18, OUTA = (size_t)ns * 81, JANG = (size_t)ns * 87;
    const floatx4 z4 = {0.f, 0.f, 0.f, 0.f};
    const int w = tid >> 6, lane = tid & 63;
    const int quad = lane >> 4, col = lane & 15;
    const int srcl = lane & 47;

    if (r5 < 2) {
        // ================= POS: 7 -> 512 -> 512 -> 3, 8 samples =================
        const int m0 = (g * 2 + r5) * 8;
        const unsigned short* wsW1 = wsBase;

        for (int i = tid; i < 512;  i += 256) { sU.p.B0[i] = pb0[i]; sU.p.B1[i] = pb1[i]; }
        for (int i = tid; i < 1536; i += 256) sU.p.W2[i] = pW2[i];
        if (tid < 112) {
            int m = tid / 14, c = tid % 14;
            float v = x[(m0 + m) * 14 + c];
            if (c < 7) sU.p.Q[m][c] = v; else sU.p.Qd[m][c - 7] = v;
        }
        __syncthreads();

        const float4* W04 = (const float4*)pW0;
        #pragma unroll
        for (int t = 0; t < 2; ++t) {
            int item = tid + t * 256;
            int s = item >> 6, k8 = item & 63;
            float q[7], w0v[7][8];
            #pragma unroll
            for (int i = 0; i < 7; i++) {
                q[i] = sU.p.Q[s][i];
                float4 a = W04[i * 128 + k8 * 2], b4 = W04[i * 128 + k8 * 2 + 1];
                w0v[i][0]=a.x; w0v[i][1]=a.y; w0v[i][2]=a.z; w0v[i][3]=a.w;
                w0v[i][4]=b4.x; w0v[i][5]=b4.y; w0v[i][6]=b4.z; w0v[i][7]=b4.w;
            }
            float hv[8], dv[8];
            #pragma unroll
            for (int jj = 0; jj < 8; jj++) {
                float z = sU.p.B0[k8 * 8 + jj];
                #pragma unroll
                for (int i = 0; i < 7; i++) z = fmaf(q[i], w0v[i][jj], z);
                float h = sig(z);
                hv[jj] = h; dv[jj] = h - h * h;
            }
            int kt = k8 >> 2, kq = k8 & 3, sw = kt & 7;
            int rr0 = s * 8;
            {
                short8 v;
                #pragma unroll
                for (int jj = 0; jj < 8; jj++) v[jj] = (short)f2bf(hv[jj]);
                *(short8*)&sA[((rr0 >> 4) * 16 + kt) * 512 + ((kq * 16 + (rr0 & 15)) ^ sw) * 8] = v;
            }
            #pragma unroll
            for (int i = 0; i < 7; i++) {
                int rr = rr0 + 1 + i;
                short8 v;
                #pragma unroll
                for (int jj = 0; jj < 8; jj++) v[jj] = (short)f2bf(dv[jj] * w0v[i][jj]);
                *(short8*)&sA[((rr >> 4) * 16 + kt) * 512 + ((kq * 16 + (rr & 15)) ^ sw) * 8] = v;
            }
        }
        __syncthreads();

        floatx4 acc[4][8];
        #pragma unroll
        for (int rt = 0; rt < 4; rt++)
            #pragma unroll
            for (int ct = 0; ct < 8; ct++) acc[rt][ct] = z4;

        const short8* bbase = (const short8*)wsW1 + (size_t)(w * 8 * 16) * 64 + lane;
        short8 bufA[8], bufB[8];
        #pragma unroll
        for (int ct = 0; ct < 8; ++ct) bufA[ct] = bbase[(ct * 16) * 64];

        for (int kt2 = 0; kt2 < 16; kt2 += 2) {
            #pragma unroll
            for (int ct = 0; ct < 8; ++ct) bufB[ct] = bbase[(ct * 16 + kt2 + 1) * 64];
            {
                const int kt = kt2, sw = kt & 7;
                short8 afr[4];
                #pragma unroll
                for (int rt = 0; rt < 4; ++rt)
                    afr[rt] = *(const short8*)&sA[(rt * 16 + kt) * 512 + (lane ^ sw) * 8];
                #pragma unroll
                for (int ct = 0; ct < 8; ++ct)
                    #pragma unroll
                    for (int rt = 0; rt < 4; ++rt)
                        acc[rt][ct] = __builtin_amdgcn_mfma_f32_16x16x32_bf16(afr[rt], bufA[ct], acc[rt][ct], 0, 0, 0);
            }
            if (kt2 + 2 < 16) {
                #pragma unroll
                for (int ct = 0; ct < 8; ++ct) bufA[ct] = bbase[(ct * 16 + kt2 + 2) * 64];
            }
            {
                const int kt = kt2 + 1, sw = kt & 7;
                short8 afr[4];
                #pragma unroll
                for (int rt = 0; rt < 4; ++rt)
                    afr[rt] = *(const short8*)&sA[(rt * 16 + kt) * 512 + (lane ^ sw) * 8];
                #pragma unroll
                for (int ct = 0; ct < 8; ++ct)
                    #pragma unroll
                    for (int rt = 0; rt < 4; ++rt)
                        acc[rt][ct] = __builtin_amdgcn_mfma_f32_16x16x32_bf16(afr[rt], bufB[ct], acc[rt][ct], 0, 0, 0);
            }
        }

        float ep[4][4][3];
        #pragma unroll
        for (int a = 0; a < 4; a++) for (int b = 0; b < 4; b++) for (int c = 0; c < 3; c++) ep[a][b][c] = 0.f;

        #pragma unroll
        for (int ct = 0; ct < 8; ++ct) {
            const int n = w * 128 + ct * 16 + col;
            const float b1n = sU.p.B1[n];
            const float w20 = sU.p.W2[n * 3], w21 = sU.p.W2[n * 3 + 1], w22 = sU.p.W2[n * 3 + 2];
            #pragma unroll
            for (int rt = 0; rt < 4; ++rt) {
                float z2c = __shfl(acc[rt][ct][0], srcl);
                float h2 = sig(z2c + b1n);
                float d2 = h2 - h2 * h2;
                #pragma unroll
                for (int r = 0; r < 4; ++r) {
                    float gg = ((quad & 1) == 0 && r == 0) ? h2 : d2 * acc[rt][ct][r];
                    ep[rt][r][0] = fmaf(gg, w20, ep[rt][r][0]);
                    ep[rt][r][1] = fmaf(gg, w21, ep[rt][r][1]);
                    ep[rt][r][2] = fmaf(gg, w22, ep[rt][r][2]);
                }
            }
        }

        #pragma unroll
        for (int mask = 1; mask <= 8; mask <<= 1)
            #pragma unroll
            for (int a = 0; a < 4; a++)
                #pragma unroll
                for (int b = 0; b < 4; b++)
                    #pragma unroll
                    for (int c = 0; c < 3; c++)
                        ep[a][b][c] += __shfl_xor(ep[a][b][c], mask);
        if (col == 0) {
            #pragma unroll
            for (int rt = 0; rt < 4; ++rt)
                #pragma unroll
                for (int r = 0; r < 4; ++r) {
                    int row = rt * 16 + quad * 4 + r;
                    sU.p.Acc[w][row][0] = ep[rt][r][0];
                    sU.p.Acc[w][row][1] = ep[rt][r][1];
                    sU.p.Acc[w][row][2] = ep[rt][r][2];
                }
        }
        __syncthreads();

        if (tid < 192) {
            int row = tid / 3, j = tid % 3;
            float v = sU.p.Acc[0][row][j] + sU.p.Acc[1][row][j] + sU.p.Acc[2][row][j] + sU.p.Acc[3][row][j];
            int s = row >> 3, i = row & 7;
            size_t M = m0 + s;
            if (i == 0) { v += pb2[j]; out[M * 18 + j] = v; out[OUTA + M * 6 + j] = v; }
            else        { out[JTOT + M * 63 + j * 7 + (i - 1)] = v;
                          out[JANG + M * 42 + j * 7 + (i - 1)] = v; }
            sU.p.Sum[row][j] = v;
        }
        __syncthreads();
        if (tid < 24) {
            int s = tid / 3, j = tid % 3;
            float vel = 0.f;
            #pragma unroll
            for (int i = 0; i < 7; i++) vel = fmaf(sU.p.Sum[s * 8 + 1 + i][j], sU.p.Qd[s][i], vel);
            out[(size_t)(m0 + s) * 18 + 9 + j] = vel;
        }
    } else {
        // ================= RPY: 7 -> 256 -> 256 -> 2, 16 samples =================
        const int h = r5 - 2;
        const int m0 = g * 16;
        const float* W0 = (h == 0) ? rW0_ : (h == 1) ? piW0 : yW0;
        const float* b0 = (h == 0) ? rb0_ : (h == 1) ? pib0 : yb0;
        const float* b1 = (h == 0) ? rb1_ : (h == 1) ? pib1 : yb1;
        const float* W2 = (h == 0) ? rW2_ : (h == 1) ? piW2 : yW2;
        const float* b2 = (h == 0) ? rb2_ : (h == 1) ? pib2 : yb2;
        const unsigned short* wsW1 = wsBase + 262144 + h * 65536;

        if (tid < 256) { sU.r.B0[tid] = b0[tid]; sU.r.B1[tid] = b1[tid]; }
        for (int i = tid; i < 512; i += 256) sU.r.W2[i] = W2[i];
        if (tid < 224) {
            int m = tid / 14, c = tid % 14;
            float v = x[(m0 + m) * 14 + c];
            if (c < 7) sU.r.Q[m][c] = v; else sU.r.Qd[m][c - 7] = v;
        }
        __syncthreads();

        const float4* W04 = (const float4*)W0;
        #pragma unroll
        for (int t = 0; t < 2; ++t) {
            int item = tid + t * 256;
            int s = item >> 5, k8 = item & 31;
            float q[7], w0v[7][8];
            #pragma unroll
            for (int i = 0; i < 7; i++) {
                q[i] = sU.r.Q[s][i];
                float4 a = W04[i * 64 + k8 * 2], b4 = W04[i * 64 + k8 * 2 + 1];
                w0v[i][0]=a.x; w0v[i][1]=a.y; w0v[i][2]=a.z; w0v[i][3]=a.w;
                w0v[i][4]=b4.x; w0v[i][5]=b4.y; w0v[i][6]=b4.z; w0v[i][7]=b4.w;
            }
            float hv[8], dv[8];
            #pragma unroll
            for (int jj = 0; jj < 8; jj++) {
                float z = sU.r.B0[k8 * 8 + jj];
                #pragma unroll
                for (int i = 0; i < 7; i++) z = fmaf(q[i], w0v[i][jj], z);
                float hh = sig(z);
                hv[jj] = hh; dv[jj] = hh - hh * hh;
            }
            int kt = k8 >> 2, kq = k8 & 3, sw = kt & 7;
            int rr0 = s * 8;
            {
                short8 v;
                #pragma unroll
                for (int jj = 0; jj < 8; jj++) v[jj] = (short)f2bf(hv[jj]);
                *(short8*)&sA[((rr0 >> 4) * 8 + kt) * 512 + ((kq * 16 + (rr0 & 15)) ^ sw) * 8] = v;
            }
            #pragma unroll
            for (int i = 0; i < 7; i++) {
                int rr = rr0 + 1 + i;
                short8 v;
                #pragma unroll
                for (int jj = 0; jj < 8; jj++) v[jj] = (short)f2bf(dv[jj] * w0v[i][jj]);
                *(short8*)&sA[((rr >> 4) * 8 + kt) * 512 + ((kq * 16 + (rr & 15)) ^ sw) * 8] = v;
            }
        }
        __syncthreads();

        floatx4 acc[8][4];
        #pragma unroll
        for (int rt = 0; rt < 8; rt++)
            #pragma unroll
            for (int ct = 0; ct < 4; ct++) acc[rt][ct] = z4;

        const short8* bbase = (const short8*)wsW1 + (size_t)(w * 4 * 8) * 64 + lane;
        short8 bufA[4], bufB[4];
        #pragma unroll
        for (int ct = 0; ct < 4; ++ct) bufA[ct] = bbase[(ct * 8) * 64];

        for (int kt2 = 0; kt2 < 8; kt2 += 2) {
            #pragma unroll
            for (int ct = 0; ct < 4; ++ct) bufB[ct] = bbase[(ct * 8 + kt2 + 1) * 64];
            {
                const int kt = kt2, sw = kt & 7;
                short8 afr[8];
                #pragma unroll
                for (int rt = 0; rt < 8; ++rt)
                    afr[rt] = *(const short8*)&sA[(rt * 8 + kt) * 512 + (lane ^ sw) * 8];
                #pragma unroll
                for (int ct = 0; ct < 4; ++ct)
                    #pragma unroll
                    for (int rt = 0; rt < 8; ++rt)
                        acc[rt][ct] = __builtin_amdgcn_mfma_f32_16x16x32_bf16(afr[rt], bufA[ct], acc[rt][ct], 0, 0, 0);
            }
            if (kt2 + 2 < 8) {
                #pragma unroll
                for (int ct = 0; ct < 4; ++ct) bufA[ct] = bbase[(ct * 8 + kt2 + 2) * 64];
            }
            {
                const int kt = kt2 + 1, sw = kt & 7;
                short8 afr[8];
                #pragma unroll
                for (int rt = 0; rt < 8; ++rt)
                    afr[rt] = *(const short8*)&sA[(rt * 8 + kt) * 512 + (lane ^ sw) * 8];
                #pragma unroll
                for (int ct = 0; ct < 4; ++ct)
                    #pragma unroll
                    for (int rt = 0; rt < 8; ++rt)
                        acc[rt][ct] = __builtin_amdgcn_mfma_f32_16x16x32_bf16(afr[rt], bufB[ct], acc[rt][ct], 0, 0, 0);
            }
        }

        float ep[8][4][2];
        #pragma unroll
        for (int a = 0; a < 8; a++) for (int b = 0; b < 4; b++) for (int c = 0; c < 2; c++) ep[a][b][c] = 0.f;

        #pragma unroll
        for (int ct = 0; ct < 4; ++ct) {
            const int n = w * 64 + ct * 16 + col;
            const float b1n = sU.r.B1[n];
            const float w20 = sU.r.W2[n * 2], w21 = sU.r.W2[n * 2 + 1];
            #pragma unroll
            for (int rt = 0; rt < 8; ++rt) {
                float z2c = __shfl(acc[rt][ct][0], srcl);
                float h2 = sig(z2c + b1n);
                float d2 = h2 - h2 * h2;
                #pragma unroll
                for (int r = 0; r < 4; ++r) {
                    float gg = ((quad & 1) == 0 && r == 0) ? h2 : d2 * acc[rt][ct][r];
                    ep[rt][r][0] = fmaf(gg, w20, ep[rt][r][0]);
                    ep[rt][r][1] = fmaf(gg, w21, ep[rt][r][1]);
                }
            }
        }

        #pragma unroll
        for (int mask = 1; mask <= 8; mask <<= 1)
            #pragma unroll
            for (int a = 0; a < 8; a++)
                #pragma unroll
                for (int b = 0; b < 4; b++)
                    #pragma unroll
                    for (int c = 0; c < 2; c++)
                        ep[a][b][c] += __shfl_xor(ep[a][b][c], mask);
        if (col == 0) {
            #pragma unroll
            for (int rt = 0; rt < 8; ++rt)
                #pragma unroll
                for (int r = 0; r < 4; ++r) {
                    int row = rt * 16 + quad * 4 + r;
                    sU.r.Acc[w][row][0] = ep[rt][r][0];
                    sU.r.Acc[w][row][1] = ep[rt][r][1];
                }
        }
        __syncthreads();

        if (tid < 256) {
            int row = tid >> 1, j = tid & 1;
            float v = sU.r.Acc[0][row][j] + sU.r.Acc[1][row][j] + sU.r.Acc[2][row][j] + sU.r.Acc[3][row][j];
            if ((row & 7) == 0) v += b2[j];
            sU.r.Sum[row][j] = v;
        }
        __syncthreads();

        if (tid < 16) {
            int s = tid;
            size_t M = m0 + s;
            float y0 = sU.r.Sum[s * 8][0], y1 = sU.r.Sum[s * 8][1];
            float sv = sinf(y0), cv = cosf(y1);
            out[M * 18 + 3 + h] = sv;
            out[M * 18 + 6 + h] = cv;
            out[OUTA + M * 6 + 3 + h] = atan2f(sv, cv);
            float f0 = cosf(y0), f1 = -sinf(y1);
            float inv = 1.0f / fmaf(sv, sv, cv * cv);
            float v0 = 0.f, v1 = 0.f;
            #pragma unroll
            for (int i = 0; i < 7; i++) {
                float r0 = f0 * sU.r.Sum[s * 8 + 1 + i][0];
                float r1 = f1 * sU.r.Sum[s * 8 + 1 + i][1];
                out[JTOT + M * 63 + (3 + h) * 7 + i] = r0;
                out[JTOT + M * 63 + (6 + h) * 7 + i] = r1;
                out[JANG + M * 42 + (3 + h) * 7 + i] = (cv * r0 - sv * r1) * inv;
                v0 = fmaf(r0, sU.r.Qd[s][i], v0);
                v1 = fmaf(r1, sU.r.Qd[s][i], v1);
            }
            out[M * 18 + 12 + h] = v0;
            out[M * 18 + 15 + h] = v1;
        }
    }
}

extern "C" void kernel_launch(void* const* d_in, const int* in_sizes, int n_in,
                              void* d_out, int out_size, void* d_ws, size_t ws_size,
                              hipStream_t stream) {
    (void)n_in; (void)out_size; (void)ws_size;
    const float* x = (const float*)d_in[0];
    float* out = (float*)d_out;
    unsigned short* ws = (unsigned short*)d_ws;
    const int ns = in_sizes[0] / 14;

    convert_w1<<<dim3((512 * 512) / 256), 256, 0, stream>>>((const float*)d_in[3],  ws,          512, 9);
    convert_w1<<<dim3((256 * 256) / 256), 256, 0, stream>>>((const float*)d_in[9],  ws + 262144, 256, 8);
    convert_w1<<<dim3((256 * 256) / 256), 256, 0, stream>>>((const float*)d_in[15], ws + 327680, 256, 8);
    convert_w1<<<dim3((256 * 256) / 256), 256, 0, stream>>>((const float*)d_in[21], ws + 393216, 256, 8);

    // 5120 blocks: per group of 5 -> 2 pos tiles + 3 rpy heads (1024 groups)
    fused_mfma<<<dim3((ns / 8 / 2) * 5), 256, 65536, stream>>>(
        x,
        (const float*)d_in[1],  (const float*)d_in[2],  (const float*)d_in[4],
        (const float*)d_in[5],  (const float*)d_in[6],
        (const float*)d_in[7],  (const float*)d_in[8],  (const float*)d_in[10],
        (const float*)d_in[11], (const float*)d_in[12],
        (const float*)d_in[13], (const float*)d_in[14], (const float*)d_in[16],
        (const float*)d_in[17], (const float*)d_in[18],
        (const float*)d_in[19], (const float*)d_in[20], (const float*)d_in[22],
        (const float*)d_in[23], (const float*)d_in[24],
        ws, out, ns);
}